// Round 7
// baseline (604.181 us; speedup 1.0000x reference)
//
#include <hip/hip_runtime.h>
#include <hip/hip_bf16.h>

typedef __bf16 bf16_t;
typedef bf16_t bf16x8 __attribute__((ext_vector_type(8)));
typedef float f32x4 __attribute__((ext_vector_type(4)));

constexpr int D_DIM = 1024;
constexpr int S_DIM = 4096;
constexpr int B_DIM = 4;

// ---------------- elementwise cast X: fp32 -> bf16 ----------------
__global__ void cast_f32_bf16(const float* __restrict__ in, bf16_t* __restrict__ out) {
  size_t i = ((size_t)blockIdx.x * blockDim.x + threadIdx.x) * 8;
  float4 a = *(const float4*)(in + i);
  float4 b = *(const float4*)(in + i + 4);
  bf16x8 o;
  o[0] = (bf16_t)a.x; o[1] = (bf16_t)a.y; o[2] = (bf16_t)a.z; o[3] = (bf16_t)a.w;
  o[4] = (bf16_t)b.x; o[5] = (bf16_t)b.y; o[6] = (bf16_t)b.z; o[7] = (bf16_t)b.w;
  *(bf16x8*)(out + i) = o;
}

// ---------------- transpose + cast weight: [1024][1024] f32 -> bf16 transposed ----
__global__ void transpose_cast_1024(const float* __restrict__ in, bf16_t* __restrict__ out) {
  __shared__ float t[32][33];
  int x0 = blockIdx.x * 32, y0 = blockIdx.y * 32;
#pragma unroll
  for (int i = 0; i < 32; i += 8)
    t[threadIdx.y + i][threadIdx.x] =
        in[(size_t)(y0 + threadIdx.y + i) * D_DIM + (x0 + threadIdx.x)];
  __syncthreads();
#pragma unroll
  for (int i = 0; i < 32; i += 8)
    out[(size_t)(x0 + threadIdx.y + i) * D_DIM + (y0 + threadIdx.x)] =
        (bf16_t)t[threadIdx.x][threadIdx.y + i];
}

// ======== 256x256 GEMM, BK=32, ONE phase per K-tile, 4-deep LDS ring ========
// 512 threads = 8 waves (2M x 4N), per-wave out 128x64 (8 x 4 16x16 frags).
// Per phase: 12 ds_read_b128 + 4 global_load_lds (stage tile t+3) + 32 MFMA.
// LDS: 4 ring buffers x (A 16KB + B 16KB) = 128 KB. Layout [256][32] row-major,
// natively conflict-free for this fragment read (8 granules x 8 lanes uniform);
// staging is fully LINEAR (both sides, rule #21 trivially satisfied).
// Counted-vmcnt ladder: steady state 12 loads in flight, vmcnt(8) drains exactly
// tile t+1 (issued 3 phases earlier) -> never waits on young loads.
constexpr int BM2 = 256, BN2 = 256;

#define VMCNT8 asm volatile("s_waitcnt vmcnt(8)" ::: "memory")
#define VMCNT4 asm volatile("s_waitcnt vmcnt(4)" ::: "memory")
#define VMCNT0 asm volatile("s_waitcnt vmcnt(0)" ::: "memory")
#define LGKM8  asm volatile("s_waitcnt lgkmcnt(8)" ::: "memory")
#define LGKM0  asm volatile("s_waitcnt lgkmcnt(0)" ::: "memory")
#define SCHEDB __builtin_amdgcn_sched_barrier(0)
#define CFENCE asm volatile("" ::: "memory")
#define BAR __builtin_amdgcn_s_barrier()
#define PRIO1 __builtin_amdgcn_s_setprio(1)
#define PRIO0 __builtin_amdgcn_s_setprio(0)

// stage one 256x32 bf16 tile (16 KB) into LDS: 2 gloads/wave, linear both sides.
__device__ __forceinline__ void stage_tile32(const bf16_t* __restrict__ g, int ld,
                                             bf16_t* lds, int tid) {
  const int w = tid >> 6, l = tid & 63;
  const int row = w * 16 + (l >> 2);     // rows 0..127 (first gload)
  const int chunk = (l & 3) * 8;         // 4 x 16B chunks per 64B row
  const bf16_t* s0 = g + (size_t)row * ld + chunk;
  bf16_t* l0 = lds + w * 512;            // wave-uniform; HW adds lane*16B
  __builtin_amdgcn_global_load_lds((const __attribute__((address_space(1))) void*)s0,
                                   (__attribute__((address_space(3))) void*)l0, 16, 0, 0);
  __builtin_amdgcn_global_load_lds(
      (const __attribute__((address_space(1))) void*)(s0 + (size_t)128 * ld),
      (__attribute__((address_space(3))) void*)(l0 + 4096), 16, 0, 0);
}

// EPI: 0 = fused QKV projection (Q,K row-major + bias; V transposed + bias)
//      2 = bf16 out, sigmoid(v*scale)   (scores -> P)
//      3 = fp32 out                      (PV -> out)
template <int EPI, bool SWAP>
__global__ __launch_bounds__(512, 2) void gemm256k32(
    const bf16_t* __restrict__ A, const bf16_t* __restrict__ Bt,
    void* __restrict__ C0, void* __restrict__ C1, void* __restrict__ C2,
    const float* __restrict__ b0, const float* __restrict__ b1, const float* __restrict__ b2,
    int K, int lda, int ldb, int ldc, float scale,
    size_t sA, size_t sB, size_t sC) {
  __shared__ __align__(16) bf16_t smem[65536];  // 128 KB: 4 x {A 8192, B 8192} elems

  const int tid = threadIdx.x;
  const int lane = tid & 63;
  const int w = tid >> 6;
  const int wr = (w >> 2) * 128;     // wave row base (2 M-waves)
  const int wc = (w & 3) * 64;       // wave col base (4 N-waves)
  const int fm = lane & 15;
  const int fko = (lane >> 4) * 8;   // K-offset within 32-col tile

  // T1 bijective XCD remap (all grids have nwg % 8 == 0)
  const int nx = gridDim.x, ny = gridDim.y;
  const int nwg = nx * ny * gridDim.z;
  const int flat = blockIdx.x + nx * (blockIdx.y + ny * blockIdx.z);
  const int q = nwg >> 3;
  const int L = (flat & 7) * q + (flat >> 3);
  const int lx = L % nx;
  const int lt = L / nx;
  const int ly = lt % ny;
  const int lz = lt / ny;

  const int bx = SWAP ? ly : lx;
  const int by = SWAP ? lx : ly;

  const bf16_t* Ag = A + (size_t)lz * sA + (size_t)by * BM2 * lda;
  const bf16_t* Bg = Bt + (size_t)lz * sB + (size_t)bx * BN2 * ldb;

  f32x4 acc[8][4] = {};
  bf16x8 af[8], bfr[4];

  const int NT = K / 32;  // K-tiles (>= 32 for all our shapes)

  // prologue: stage tiles 0,1,2 into ring bufs 0,1,2 (12 vm events); drain tile0.
  stage_tile32(Ag, lda, smem, tid);
  stage_tile32(Bg, ldb, smem + 8192, tid);
  stage_tile32(Ag + 32, lda, smem + 16384, tid);
  stage_tile32(Bg + 32, ldb, smem + 16384 + 8192, tid);
  stage_tile32(Ag + 64, lda, smem + 32768, tid);
  stage_tile32(Bg + 64, ldb, smem + 32768 + 8192, tid);
  VMCNT8;  // tile0 (4 oldest) resident; tiles 1,2 in flight
  BAR;

#pragma unroll 1
  for (int t = 0; t < NT; ++t) {
    const bf16_t* As = smem + (t & 3) * 16384;
    const bf16_t* Bs = As + 8192;

    // 12 ds_read_b128: 8 A-frags + 4 B-frags for this K-tile
#pragma unroll
    for (int m = 0; m < 8; ++m)
      af[m] = *(const bf16x8*)&As[(wr + m * 16 + fm) * 32 + fko];
#pragma unroll
    for (int n = 0; n < 4; ++n)
      bfr[n] = *(const bf16x8*)&Bs[(wc + n * 16 + fm) * 32 + fko];

    // stage tile t+3 into ring buf (t+3)&3 (tile t-1's buffer: reads done at t-1)
    if (t + 3 < NT) {
      bf16_t* dst = smem + ((t + 3) & 3) * 16384;
      stage_tile32(Ag + (size_t)(t + 3) * 32, lda, dst, tid);
      stage_tile32(Bg + (size_t)(t + 3) * 32, ldb, dst + 8192, tid);
    }

    LGKM8; CFENCE; BAR;
    LGKM0; SCHEDB;
    PRIO1;
#pragma unroll
    for (int m = 0; m < 8; ++m)
#pragma unroll
      for (int n = 0; n < 4; ++n)
        acc[m][n] = __builtin_amdgcn_mfma_f32_16x16x32_bf16(af[m], bfr[n], acc[m][n], 0, 0, 0);
    PRIO0;

    // counted-vmcnt ladder: drain exactly tile t+1 (needed next phase)
    const int rem = NT - 1 - t;
    if (rem >= 3) { VMCNT8; }
    else if (rem == 2) { VMCNT4; }
    else if (rem == 1) { VMCNT0; }
    BAR;
  }

  // epilogue: C/D layout col=lane&15, row=(lane>>4)*4+reg
  const int row0 = by * BM2 + wr + (lane >> 4) * 4;
  const int col0 = bx * BN2 + wc + fm;

  if constexpr (EPI == 0) {
    // fused QKV: N=3072; segment uniform per block (256-col blocks, 1024-col segments)
    const int seg = bx >> 2;  // 0=Q, 1=K, 2=V
    const float* bias = (seg == 0) ? b0 : (seg == 1) ? b1 : b2;
#pragma unroll
    for (int i = 0; i < 8; ++i) {
#pragma unroll
      for (int j = 0; j < 4; ++j) {
        const int n = col0 + j * 16;
        const int nl = n & 1023;
        const float bv = bias[nl];
#pragma unroll
        for (int r = 0; r < 4; ++r) {
          const int m = row0 + i * 16 + r;
          float v = acc[i][j][r] + bv;
          if (seg < 2) {
            bf16_t* C = (bf16_t*)(seg == 0 ? C0 : C1);
            C[(size_t)m * D_DIM + nl] = (bf16_t)v;
          } else {
            // Vt[b][n][s]: b = m>>12, s = m&4095
            bf16_t* C = (bf16_t*)C2;
            C[((size_t)(m >> 12) << 22) + (size_t)nl * S_DIM + (m & (S_DIM - 1))] = (bf16_t)v;
          }
        }
      }
    }
  } else {
#pragma unroll
    for (int i = 0; i < 8; ++i) {
#pragma unroll
      for (int j = 0; j < 4; ++j) {
        const int n = col0 + j * 16;
#pragma unroll
        for (int r = 0; r < 4; ++r) {
          const int m = row0 + i * 16 + r;
          float v = acc[i][j][r];
          if constexpr (EPI == 2) {
            bf16_t* C = (bf16_t*)C0 + (size_t)lz * sC;
            float s = 1.0f / (1.0f + __expf(-v * scale));
            C[(size_t)m * ldc + n] = (bf16_t)s;
          } else {
            float* C = (float*)C0 + (size_t)lz * sC;
            C[(size_t)m * ldc + n] = v;
          }
        }
      }
    }
  }
}

extern "C" void kernel_launch(void* const* d_in, const int* in_sizes, int n_in,
                              void* d_out, int out_size, void* d_ws, size_t ws_size,
                              hipStream_t stream) {
  const float* X  = (const float*)d_in[0];
  const float* Wq = (const float*)d_in[1];
  const float* bq = (const float*)d_in[2];
  const float* Wk = (const float*)d_in[3];
  const float* bk = (const float*)d_in[4];
  const float* Wv = (const float*)d_in[5];
  const float* bv = (const float*)d_in[6];
  float* out = (float*)d_out;

  const int M = B_DIM * S_DIM;                 // 16384
  const size_t SD = (size_t)S_DIM * D_DIM;
  const size_t E  = (size_t)M * D_DIM;
  const size_t PE1 = (size_t)S_DIM * S_DIM;
  const size_t WE = (size_t)D_DIM * D_DIM;

  size_t need4 = (4 * PE1 + 3 * E + 3 * WE) * sizeof(bf16_t);
  const int PB = (ws_size >= need4) ? 4 : 1;
  const size_t psz = (size_t)PB * PE1;

  bf16_t* ws = (bf16_t*)d_ws;
  bf16_t* P   = ws;
  bf16_t* Xb  = ws;      // aliases P: Xb dead before first P write
  bf16_t* Qb  = ws + psz;
  bf16_t* Kb  = Qb + E;
  bf16_t* Vt  = Kb + E;  // [B][D][S]
  bf16_t* Wt  = Vt + E;  // [3072][1024]

  cast_f32_bf16<<<dim3((unsigned)(E / 8 / 256)), dim3(256), 0, stream>>>(X, Xb);

  dim3 tg(D_DIM / 32, D_DIM / 32), tb(32, 8);
  transpose_cast_1024<<<tg, tb, 0, stream>>>(Wq, Wt);
  transpose_cast_1024<<<tg, tb, 0, stream>>>(Wk, Wt + WE);
  transpose_cast_1024<<<tg, tb, 0, stream>>>(Wv, Wt + 2 * WE);

  // 3. fused QKV projection: [16384,1024] x [3072,1024]^T
  dim3 pg(3 * D_DIM / BN2, M / BM2, 1);  // (12, 64) -> 768 blocks, %8==0
  gemm256k32<0, false><<<pg, dim3(512), 0, stream>>>(
      Xb, Wt, Qb, Kb, Vt, bq, bk, bv, D_DIM, D_DIM, D_DIM, D_DIM, 1.0f, 0, 0, 0);

  // 4/5. scores (sigmoid fused) then PV, PB batches at a time
  const float scale = 0.03125f;  // 1/sqrt(1024)
  for (int b0 = 0; b0 < B_DIM; b0 += PB) {
    dim3 sg(S_DIM / BN2, S_DIM / BM2, PB);  // (16, 16, PB)
    gemm256k32<2, false><<<sg, dim3(512), 0, stream>>>(
        Qb + (size_t)b0 * SD, Kb + (size_t)b0 * SD, P,
        nullptr, nullptr, nullptr, nullptr, nullptr,
        D_DIM, D_DIM, D_DIM, S_DIM, scale, SD, SD, PE1);
    dim3 vg(S_DIM / BM2, D_DIM / BN2, PB);  // (16, 4, PB)
    gemm256k32<3, true><<<vg, dim3(512), 0, stream>>>(
        P, Vt + (size_t)b0 * SD, out + (size_t)b0 * SD,
        nullptr, nullptr, nullptr, nullptr, nullptr,
        S_DIM, S_DIM, S_DIM, D_DIM, 1.0f, PE1, SD, SD);
  }
}

// Round 8
// 560.712 us; speedup vs baseline: 1.0775x; 1.0775x over previous
//
#include <hip/hip_runtime.h>
#include <hip/hip_bf16.h>

typedef __bf16 bf16_t;
typedef bf16_t bf16x8 __attribute__((ext_vector_type(8)));
typedef float f32x4 __attribute__((ext_vector_type(4)));

constexpr int D_DIM = 1024;
constexpr int S_DIM = 4096;
constexpr int B_DIM = 4;

// ---------------- elementwise cast X: fp32 -> bf16 ----------------
__global__ void cast_f32_bf16(const float* __restrict__ in, bf16_t* __restrict__ out) {
  size_t i = ((size_t)blockIdx.x * blockDim.x + threadIdx.x) * 8;
  float4 a = *(const float4*)(in + i);
  float4 b = *(const float4*)(in + i + 4);
  bf16x8 o;
  o[0] = (bf16_t)a.x; o[1] = (bf16_t)a.y; o[2] = (bf16_t)a.z; o[3] = (bf16_t)a.w;
  o[4] = (bf16_t)b.x; o[5] = (bf16_t)b.y; o[6] = (bf16_t)b.z; o[7] = (bf16_t)b.w;
  *(bf16x8*)(out + i) = o;
}

// ---------------- transpose + cast weight: [1024][1024] f32 -> bf16 transposed ----
__global__ void transpose_cast_1024(const float* __restrict__ in, bf16_t* __restrict__ out) {
  __shared__ float t[32][33];
  int x0 = blockIdx.x * 32, y0 = blockIdx.y * 32;
#pragma unroll
  for (int i = 0; i < 32; i += 8)
    t[threadIdx.y + i][threadIdx.x] =
        in[(size_t)(y0 + threadIdx.y + i) * D_DIM + (x0 + threadIdx.x)];
  __syncthreads();
#pragma unroll
  for (int i = 0; i < 32; i += 8)
    out[(size_t)(x0 + threadIdx.y + i) * D_DIM + (y0 + threadIdx.x)] =
        (bf16_t)t[threadIdx.x][threadIdx.y + i];
}

// ======== 256x256 GEMM, BK=64, ONE fat phase per K-tile, 2-slot LDS dbuf ========
// 512 threads = 8 waves (2M x 4N), per-wave out 128x64 (8x4 16x16 frags).
// Per phase: 24 ds_read_b128 (two 12-read halves) + 64 MFMA (two 32-MFMA
// independent clusters) + 8 gloads (stage t+2 into the slot just read) + 2
// barriers per K=64 (vs round-4's 8). Slot = 48KB {A 32KB, B 32KB... A halves
// +0/+16384, B halves +32768/+49152? -> A:[0,32KB) rows 0..255, B:[32KB,64KB)};
// stride 49152: A halves at +0,+16384; B halves at +32768,+32768+16384=+49152
// exceeds... B half2 lands at +49152 which is slot1's base — WRONG for stride
// 49152. Slot stride is 65536 minus... Final: slot stride 49152 with layout
// A0@+0, A1@+16384, B0@+32768, B1@+32768+16384 needs 65536. So slot stride =
// 65536 and total = 131072 (2 slots x 64KB) — exactly the round-4 footprint.
constexpr int BM2 = 256, BN2 = 256;
constexpr int SLOT = 65536;  // 64 KB per slot: A 32KB + B 32KB

#define VMCNT8 asm volatile("s_waitcnt vmcnt(8)" ::: "memory")
#define VMCNT0 asm volatile("s_waitcnt vmcnt(0)" ::: "memory")
#define LGKM0  asm volatile("s_waitcnt lgkmcnt(0)" ::: "memory")
#define SCHEDB __builtin_amdgcn_sched_barrier(0)
#define BAR __builtin_amdgcn_s_barrier()
#define PRIO1 __builtin_amdgcn_s_setprio(1)
#define PRIO0 __builtin_amdgcn_s_setprio(0)

__device__ __forceinline__ void stage_half(const bf16_t* __restrict__ g, int ld,
                                           char* lds, int tid) {
  const int w = tid >> 6, l = tid & 63;
  const int rw = l >> 3;          // row within this wave's 8-row group (== row&7)
  const int gl = (l & 7) ^ rw;    // swizzled source 16B-granule (rule #21 src-side)
  char* l0 = lds + w * 1024;      // wave-uniform
  const bf16_t* s0 = g + (size_t)(w * 8 + rw) * ld + gl * 8;
  __builtin_amdgcn_global_load_lds((const __attribute__((address_space(1))) void*)s0,
                                   (__attribute__((address_space(3))) void*)l0, 16, 0, 0);
  __builtin_amdgcn_global_load_lds(
      (const __attribute__((address_space(1))) void*)(s0 + (size_t)64 * ld),
      (__attribute__((address_space(3))) void*)(l0 + 8192), 16, 0, 0);
}

// stage a full K-tile (A 256x64 + B 256x64) into a slot: 8 gloads
__device__ __forceinline__ void stage_tile(const bf16_t* __restrict__ gA, int lda,
                                           const bf16_t* __restrict__ gB, int ldb,
                                           char* slot, int tid) {
  stage_half(gA, lda, slot, tid);
  stage_half(gA + (size_t)128 * lda, lda, slot + 16384, tid);
  stage_half(gB, ldb, slot + 32768, tid);
  stage_half(gB + (size_t)128 * ldb, ldb, slot + 49152, tid);
}

__device__ __forceinline__ void load_a8(const char* __restrict__ At, int wr, int fm,
                                        int kx, bf16x8 (&af)[8]) {
#pragma unroll
  for (int m = 0; m < 8; ++m)
    af[m] = *(const bf16x8*)(At + (wr + m * 16 + fm) * 128 + kx);
}

__device__ __forceinline__ void load_b4(const char* __restrict__ Bt_, int wc, int fm,
                                        int kx, bf16x8 (&bfr)[4]) {
#pragma unroll
  for (int n = 0; n < 4; ++n)
    bfr[n] = *(const bf16x8*)(Bt_ + (wc + n * 16 + fm) * 128 + kx);
}

__device__ __forceinline__ void mfma32(f32x4 (&acc)[8][4], const bf16x8 (&af)[8],
                                       const bf16x8 (&bfr)[4]) {
#pragma unroll
  for (int m = 0; m < 8; ++m)
#pragma unroll
    for (int n = 0; n < 4; ++n)
      acc[m][n] = __builtin_amdgcn_mfma_f32_16x16x32_bf16(af[m], bfr[n], acc[m][n], 0, 0, 0);
}

// EPI: 0 = fused QKV (Q,K row-major + bias; V transposed + bias)
//      2 = bf16 out, sigmoid(v*scale)   (scores -> P)
//      3 = fp32 out                      (PV -> out)
template <int EPI, bool SWAP>
__global__ __launch_bounds__(512, 2) void gemm256f(
    const bf16_t* __restrict__ A, const bf16_t* __restrict__ Bt,
    void* __restrict__ C0, void* __restrict__ C1, void* __restrict__ C2,
    const float* __restrict__ b0, const float* __restrict__ b1, const float* __restrict__ b2,
    int K, int lda, int ldb, int ldc, float scale,
    size_t sA, size_t sB, size_t sC) {
  __shared__ __align__(16) char smem[2 * SLOT];  // 128 KB

  const int tid = threadIdx.x;
  const int lane = tid & 63;
  const int w = tid >> 6;
  const int wr = (w >> 2) * 128;
  const int wc = (w & 3) * 64;
  const int fm = lane & 15;
  const int ssw = (fm & 7) << 4;
  const int kp = (lane >> 4) << 4;
  const int kxa = kp ^ ssw;
  const int kxb = (64 | kp) ^ ssw;

  // T1 bijective XCD remap (all grids have nwg % 8 == 0)
  const int nx = gridDim.x, ny = gridDim.y;
  const int nwg = nx * ny * gridDim.z;
  const int flat = blockIdx.x + nx * (blockIdx.y + ny * blockIdx.z);
  const int q = nwg >> 3;
  const int L = (flat & 7) * q + (flat >> 3);
  const int lx = L % nx;
  const int lt = L / nx;
  const int ly = lt % ny;
  const int lz = lt / ny;

  const int bx = SWAP ? ly : lx;
  const int by = SWAP ? lx : ly;

  const bf16_t* Ag = A + (size_t)lz * sA + (size_t)by * BM2 * lda;
  const bf16_t* Bg = Bt + (size_t)lz * sB + (size_t)bx * BN2 * ldb;

  f32x4 acc[8][4] = {};
  bf16x8 af[8], bfr[4];

  const int NT = K / 64;

  // prologue: tile0 -> slot0, tile1 -> slot1 (16 gloads); drain tile0, keep tile1.
  stage_tile(Ag, lda, Bg, ldb, smem, tid);
  stage_tile(Ag + 64, lda, Bg + 64, ldb, smem + SLOT, tid);
  VMCNT8;
  BAR;

#pragma unroll 1
  for (int t = 0; t < NT; ++t) {
    const char* Aslot = smem + (t & 1) * SLOT;
    const char* Bslot = Aslot + 32768;

    // K-half 0: 12 ds_reads -> 32 independent MFMAs
    load_a8(Aslot, wr, fm, kxa, af);
    load_b4(Bslot, wc, fm, kxa, bfr);
    LGKM0; SCHEDB;
    PRIO1; mfma32(acc, af, bfr); PRIO0;

    // K-half 1: 12 ds_reads -> 32 independent MFMAs
    load_a8(Aslot, wr, fm, kxb, af);
    load_b4(Bslot, wc, fm, kxb, bfr);
    LGKM0; SCHEDB;
    PRIO1; mfma32(acc, af, bfr); PRIO0;

    // all waves' reads of this slot are register-resident after their lgkm0;
    // barrier, then overwrite this slot with tile t+2.
    BAR;
    if (t + 2 < NT)
      stage_tile(Ag + (size_t)(t + 2) * 64, lda, Bg + (size_t)(t + 2) * 64, ldb,
                 (char*)smem + (t & 1) * SLOT, tid);
    // drain tile t+1 (staged one full phase ago); keep t+2 (8) in flight
    if (t + 1 < NT) { if (t + 2 < NT) { VMCNT8; } else { VMCNT0; } }
    BAR;
  }

  // epilogue: C/D layout col=lane&15, row=(lane>>4)*4+reg
  const int row0 = by * BM2 + wr + (lane >> 4) * 4;
  const int col0 = bx * BN2 + wc + fm;

  if constexpr (EPI == 0) {
    const int seg = bx >> 2;  // 0=Q, 1=K, 2=V
    const float* bias = (seg == 0) ? b0 : (seg == 1) ? b1 : b2;
#pragma unroll
    for (int i = 0; i < 8; ++i) {
#pragma unroll
      for (int j = 0; j < 4; ++j) {
        const int n = col0 + j * 16;
        const int nl = n & 1023;
        const float bv = bias[nl];
#pragma unroll
        for (int r = 0; r < 4; ++r) {
          const int m = row0 + i * 16 + r;
          float v = acc[i][j][r] + bv;
          if (seg < 2) {
            bf16_t* C = (bf16_t*)(seg == 0 ? C0 : C1);
            C[(size_t)m * D_DIM + nl] = (bf16_t)v;
          } else {
            // Vt[b][n][s]: b = m>>12, s = m&4095
            bf16_t* C = (bf16_t*)C2;
            C[((size_t)(m >> 12) << 22) + (size_t)nl * S_DIM + (m & (S_DIM - 1))] = (bf16_t)v;
          }
        }
      }
    }
  } else {
#pragma unroll
    for (int i = 0; i < 8; ++i) {
#pragma unroll
      for (int j = 0; j < 4; ++j) {
        const int n = col0 + j * 16;
#pragma unroll
        for (int r = 0; r < 4; ++r) {
          const int m = row0 + i * 16 + r;
          float v = acc[i][j][r];
          if constexpr (EPI == 2) {
            bf16_t* C = (bf16_t*)C0 + (size_t)lz * sC;
            float s = 1.0f / (1.0f + __expf(-v * scale));
            C[(size_t)m * ldc + n] = (bf16_t)s;
          } else {
            float* C = (float*)C0 + (size_t)lz * sC;
            C[(size_t)m * ldc + n] = v;
          }
        }
      }
    }
  }
}

extern "C" void kernel_launch(void* const* d_in, const int* in_sizes, int n_in,
                              void* d_out, int out_size, void* d_ws, size_t ws_size,
                              hipStream_t stream) {
  const float* X  = (const float*)d_in[0];
  const float* Wq = (const float*)d_in[1];
  const float* bq = (const float*)d_in[2];
  const float* Wk = (const float*)d_in[3];
  const float* bk = (const float*)d_in[4];
  const float* Wv = (const float*)d_in[5];
  const float* bv = (const float*)d_in[6];
  float* out = (float*)d_out;

  const int M = B_DIM * S_DIM;
  const size_t SD = (size_t)S_DIM * D_DIM;
  const size_t E  = (size_t)M * D_DIM;
  const size_t PE1 = (size_t)S_DIM * S_DIM;
  const size_t WE = (size_t)D_DIM * D_DIM;

  size_t need4 = (4 * PE1 + 3 * E + 3 * WE) * sizeof(bf16_t);
  const int PB = (ws_size >= need4) ? 4 : 1;
  const size_t psz = (size_t)PB * PE1;

  bf16_t* ws = (bf16_t*)d_ws;
  bf16_t* P   = ws;
  bf16_t* Xb  = ws;      // aliases P: Xb dead before first P write
  bf16_t* Qb  = ws + psz;
  bf16_t* Kb  = Qb + E;
  bf16_t* Vt  = Kb + E;  // [B][D][S]
  bf16_t* Wt  = Vt + E;  // [3072][1024]

  cast_f32_bf16<<<dim3((unsigned)(E / 8 / 256)), dim3(256), 0, stream>>>(X, Xb);

  dim3 tg(D_DIM / 32, D_DIM / 32), tb(32, 8);
  transpose_cast_1024<<<tg, tb, 0, stream>>>(Wq, Wt);
  transpose_cast_1024<<<tg, tb, 0, stream>>>(Wk, Wt + WE);
  transpose_cast_1024<<<tg, tb, 0, stream>>>(Wv, Wt + 2 * WE);

  // 3. fused QKV projection: [16384,1024] x [3072,1024]^T
  dim3 pg(3 * D_DIM / BN2, M / BM2, 1);  // (12, 64) -> 768 blocks
  gemm256f<0, false><<<pg, dim3(512), 0, stream>>>(
      Xb, Wt, Qb, Kb, Vt, bq, bk, bv, D_DIM, D_DIM, D_DIM, D_DIM, 1.0f, 0, 0, 0);

  // 4/5. scores (sigmoid fused) then PV
  const float scale = 0.03125f;  // 1/sqrt(1024)
  for (int b0 = 0; b0 < B_DIM; b0 += PB) {
    dim3 sg(S_DIM / BN2, S_DIM / BM2, PB);  // (16, 16, PB)
    gemm256f<2, false><<<sg, dim3(512), 0, stream>>>(
        Qb + (size_t)b0 * SD, Kb + (size_t)b0 * SD, P,
        nullptr, nullptr, nullptr, nullptr, nullptr,
        D_DIM, D_DIM, D_DIM, S_DIM, scale, SD, SD, PE1);
    dim3 vg(S_DIM / BM2, D_DIM / BN2, PB);  // (16, 4, PB)
    gemm256f<3, true><<<vg, dim3(512), 0, stream>>>(
        P, Vt + (size_t)b0 * SD, out + (size_t)b0 * SD,
        nullptr, nullptr, nullptr, nullptr, nullptr,
        S_DIM, S_DIM, S_DIM, D_DIM, 1.0f, PE1, SD, SD);
  }
}